// Round 11
// baseline (98.029 us; speedup 1.0000x reference)
//
#include <hip/hip_runtime.h>
#include <hip/hip_bf16.h>
#include <cstdint>

// EdgeMLP R11 = R10 (wave-pair hidden-split, 1 W1-read/edge) + depth-2 gather
// pipeline (R9-style): gathers for t+1 in flight across compute(t)+barrier,
// idx prefetched 2 ahead, unroll-2 with statically-named register sets.
// W2 frags in LDS to pay for the extra 32 prefetch VGPRs (ledger ~120 < 128).
// ws: [hb: nNodes*64 bf16][w1tab: 16384 bf16][w2tab: 2048 bf16]

constexpr int EMB = 64;
constexpr int HID = 128;

typedef short s16x8 __attribute__((ext_vector_type(8)));
typedef float f32x4 __attribute__((ext_vector_type(4)));

__device__ __forceinline__ unsigned short f2bf(float x) {
    unsigned u = __float_as_uint(x);
    u = (u + 0x7fffu + ((u >> 16) & 1u)) >> 16;   // RNE
    return (unsigned short)u;
}

// ---- prep 1: h fp32 -> bf16 ----
__global__ void conv_h_kernel(const float* __restrict__ h,
                              unsigned short* __restrict__ hb, int n8) {
    const int i = blockIdx.x * blockDim.x + threadIdx.x;
    if (i >= n8) return;
    const float* p = h + (size_t)i * 8;
    float4 a = *reinterpret_cast<const float4*>(p);
    float4 b = *reinterpret_cast<const float4*>(p + 4);
    unsigned short r[8];
    r[0] = f2bf(a.x); r[1] = f2bf(a.y); r[2] = f2bf(a.z); r[3] = f2bf(a.w);
    r[4] = f2bf(b.x); r[5] = f2bf(b.y); r[6] = f2bf(b.z); r[7] = f2bf(b.w);
    *reinterpret_cast<uint4*>(hb + (size_t)i * 8) = *reinterpret_cast<const uint4*>(r);
}

// ---- prep 2: W1 + W2 fragment tables (validated layouts) ----
__global__ void pack_tabs(const float* __restrict__ W1,
                          const float* __restrict__ W2,
                          unsigned short* __restrict__ tab) {
    const int i = blockIdx.x * blockDim.x + threadIdx.x;
    if (i < 16384) {
        const int j = i & 7, lane = (i >> 3) & 63, ks = (i >> 9) & 3, nt = i >> 11;
        const int k = ks * 32 + (lane >> 4) * 8 + j;
        const int n = nt * 16 + (lane & 15);
        tab[i] = f2bf(W1[(size_t)k * HID + n]);
    } else if (i < 16384 + 2048) {
        const int q = i - 16384;
        const int j = q & 7, lane = (q >> 3) & 63, ks = q >> 9;
        const int tc = lane & 15, bq = lane >> 4;
        const int mt = ks * 2 + (j >> 2), r = j & 3;
        tab[i] = (tc < 2) ? f2bf(W2[(mt * 16 + bq * 4 + r) * 2 + tc])
                          : (unsigned short)0;
    }
}

// ---- main ----
__global__ __launch_bounds__(256, 2)
void edge_mlp_r11(const unsigned short* __restrict__ hb,
                  const unsigned short* __restrict__ tab,
                  const int* __restrict__ eidx,
                  const float* __restrict__ b1,
                  const float* __restrict__ b2,
                  float* __restrict__ out, int E, int nTiles)
{
    __shared__ uint4 w1s[2048];             // 32 KB W1 fragments
    __shared__ uint4 w2s[256];              // 4 KB  W2 fragments
    __shared__ float b1s[128];              // 512 B
    __shared__ float2 pbuf[2][2][2][16];    // [parity][pair][subtile][lane] 1 KB
    {
        const uint4* src = reinterpret_cast<const uint4*>(tab);
        #pragma unroll
        for (int r = 0; r < 8; ++r)
            w1s[r * 256 + threadIdx.x] = src[r * 256 + threadIdx.x];
        w2s[threadIdx.x] = src[2048 + threadIdx.x];
        if (threadIdx.x < 128) b1s[threadIdx.x] = b1[threadIdx.x];
    }
    __syncthreads();

    const int t = threadIdx.x, wid = t >> 6, lane = t & 63;
    const int tc = lane & 15, bq = lane >> 4;
    const int pairId = wid >> 1, half = wid & 1;

    const s16x8* wf  = reinterpret_cast<const s16x8*>(w1s) + lane;  // + (ntG*4+ks)*64
    const s16x8* wf2 = reinterpret_cast<const s16x8*>(w2s) + lane;  // + ks2*64
    const float* b1v = b1s + half * 64 + bq * 4;                    // + nt*16

    const float a20 = (half == 0 && bq == 0) ? b2[0] : 0.f;
    const float a21 = (half == 0 && bq == 0) ? b2[1] : 0.f;

    const int stride = gridDim.x * 2;
    int bt = blockIdx.x * 2;
    if (bt >= nTiles) return;   // uniform per block

    int sA0 = 0, dA0 = 0, sB0 = 0, dB0 = 0;
    int sA1 = 0, dA1 = 0, sB1 = 0, dB1 = 0;
    s16x8 xA0[4], xB0[4], xA1[4], xB1[4];

    auto LOADIDX = [&](int bt_, int& sA, int& dA, int& sB, int& dB) {
        const int tl = bt_ + pairId;
        if (tl < nTiles) {
            const int base = tl * 32;
            const int eA = min(base + tc, E - 1);
            const int eB = min(base + 16 + tc, E - 1);
            sA = eidx[eA]; dA = eidx[E + eA];
            sB = eidx[eB]; dB = eidx[E + eB];
        } else { sA = 0; dA = 0; sB = 0; dB = 0; }
    };
    auto GATHER = [&](int sA, int dA, int sB, int dB,
                      s16x8 (&xfA)[4], s16x8 (&xfB)[4]) {
        const s16x8* ps = reinterpret_cast<const s16x8*>(hb + (size_t)sA * EMB + bq * 8);
        const s16x8* pd = reinterpret_cast<const s16x8*>(hb + (size_t)dA * EMB + bq * 8);
        xfA[0] = ps[0]; xfA[1] = ps[4]; xfA[2] = pd[0]; xfA[3] = pd[4];
        const s16x8* qs = reinterpret_cast<const s16x8*>(hb + (size_t)sB * EMB + bq * 8);
        const s16x8* qd = reinterpret_cast<const s16x8*>(hb + (size_t)dB * EMB + bq * 8);
        xfB[0] = qs[0]; xfB[1] = qs[4]; xfB[2] = qd[0]; xfB[3] = qd[4];
    };
    auto COMPUTE = [&](int bt_, int par, s16x8 (&xfA)[4], s16x8 (&xfB)[4]) {
        const int tile = bt_ + pairId;
        const bool active = (tile < nTiles);
        float2 oA = make_float2(0.f, 0.f), oB = make_float2(0.f, 0.f);
        if (active) {
            // layer 1: this wave's 4 nt tiles (hidden half*64..+63), both sub-tiles
            f32x4 accA[4], accB[4];
            #pragma unroll
            for (int nt = 0; nt < 4; ++nt) {
                const f32x4 ini = *reinterpret_cast<const f32x4*>(b1v + nt * 16);
                const s16x8 w = wf[((half * 4 + nt) * 4) * 64];
                accA[nt] = __builtin_amdgcn_mfma_f32_16x16x32_bf16(w, xfA[0], ini, 0, 0, 0);
                accB[nt] = __builtin_amdgcn_mfma_f32_16x16x32_bf16(w, xfB[0], ini, 0, 0, 0);
            }
            #pragma unroll
            for (int ks = 1; ks < 4; ++ks)
                #pragma unroll
                for (int nt = 0; nt < 4; ++nt) {
                    const s16x8 w = wf[((half * 4 + nt) * 4 + ks) * 64];
                    accA[nt] = __builtin_amdgcn_mfma_f32_16x16x32_bf16(w, xfA[ks], accA[nt], 0, 0, 0);
                    accB[nt] = __builtin_amdgcn_mfma_f32_16x16x32_bf16(w, xfB[ks], accB[nt], 0, 0, 0);
                }

            // layer-2 partial (this wave's ks2 pair, frags from LDS)
            const s16x8 w2r0 = wf2[(half * 2 + 0) * 64];
            const s16x8 w2r1 = wf2[(half * 2 + 1) * 64];
            #pragma unroll
            for (int st = 0; st < 2; ++st) {
                const f32x4* acc = st ? accB : accA;
                f32x4 o = {a20, a21, 0.f, 0.f};
                #pragma unroll
                for (int q = 0; q < 2; ++q) {
                    s16x8 p;
                    #pragma unroll
                    for (int jj = 0; jj < 4; ++jj) {
                        const int mt = q * 2 + (jj >> 1), r = (jj & 1) * 2;
                        float2 v = make_float2(fmaxf(acc[mt][r], 0.f),
                                               fmaxf(acc[mt][r + 1], 0.f));
                        __hip_bfloat162 bb = __float22bfloat162_rn(v);
                        reinterpret_cast<unsigned*>(&p)[jj] = *reinterpret_cast<unsigned*>(&bb);
                    }
                    o = __builtin_amdgcn_mfma_f32_16x16x32_bf16(q ? w2r1 : w2r0, p, o, 0, 0, 0);
                }
                if (st == 0) oA = make_float2(o[0], o[1]);
                else         oB = make_float2(o[0], o[1]);
            }

            if (half == 1 && lane < 16) {
                pbuf[par][pairId][0][lane] = oA;
                pbuf[par][pairId][1][lane] = oB;
            }
        }

        __syncthreads();   // uniform: all waves call COMPUTE every phase

        if (active && half == 0 && lane < 16) {
            const float2 qA = pbuf[par][pairId][0][lane];
            const float2 qB = pbuf[par][pairId][1][lane];
            const int base = tile * 32;
            if (base + lane < E)
                *reinterpret_cast<float2*>(out + (size_t)(base + lane) * 2) =
                    make_float2(oA.x + qA.x, oA.y + qA.y);
            if (base + 16 + lane < E)
                *reinterpret_cast<float2*>(out + (size_t)(base + 16 + lane) * 2) =
                    make_float2(oB.x + qB.x, oB.y + qB.y);
        }
    };

    // ---- prologue: tile t0 gathered, idx t1 in flight ----
    LOADIDX(bt, sA0, dA0, sB0, dB0);
    GATHER(sA0, dA0, sB0, dB0, xA0, xB0);
    LOADIDX(bt + stride, sA1, dA1, sB1, dB1);

    while (true) {
        // phase 0: prefetch gather(t+1) via idx set1; idx(t+2) -> set0; compute t
        GATHER(sA1, dA1, sB1, dB1, xA1, xB1);
        LOADIDX(bt + 2 * stride, sA0, dA0, sB0, dB0);
        COMPUTE(bt, 0, xA0, xB0);
        bt += stride;
        if (bt >= nTiles) break;

        // phase 1: mirror with sets swapped
        GATHER(sA0, dA0, sB0, dB0, xA0, xB0);
        LOADIDX(bt + 2 * stride, sA1, dA1, sB1, dB1);
        COMPUTE(bt, 1, xA1, xB1);
        bt += stride;
        if (bt >= nTiles) break;
    }
}

// ---- fallback (ws too small; correct but slow) ----
__global__ void edge_mlp_naive(const float* __restrict__ h, const int* __restrict__ eidx,
                               const float* __restrict__ W1, const float* __restrict__ b1,
                               const float* __restrict__ W2, const float* __restrict__ b2,
                               float* __restrict__ out, int E) {
    const int e = blockIdx.x * 256 + threadIdx.x;
    if (e >= E) return;
    const float* hs = h + (size_t)eidx[e] * EMB;
    const float* hd = h + (size_t)eidx[E + e] * EMB;
    float o0 = b2[0], o1 = b2[1];
    for (int j = 0; j < HID; ++j) {
        float a = b1[j];
        for (int k = 0; k < EMB; ++k)
            a += hs[k] * W1[(size_t)k * HID + j] + hd[k] * W1[(size_t)(k + EMB) * HID + j];
        a = fmaxf(a, 0.f);
        o0 = fmaf(a, W2[j * 2 + 0], o0);
        o1 = fmaf(a, W2[j * 2 + 1], o1);
    }
    out[(size_t)e * 2 + 0] = o0;
    out[(size_t)e * 2 + 1] = o1;
}

extern "C" void kernel_launch(void* const* d_in, const int* in_sizes, int n_in,
                              void* d_out, int out_size, void* d_ws, size_t ws_size,
                              hipStream_t stream)
{
    const float* h  = (const float*)d_in[0];
    const int*   ei = (const int*)d_in[1];
    const float* W1 = (const float*)d_in[2];
    const float* b1 = (const float*)d_in[3];
    const float* W2 = (const float*)d_in[4];
    const float* b2 = (const float*)d_in[5];
    float* out = (float*)d_out;

    const int nNodes = in_sizes[0] / EMB;
    const int E      = in_sizes[1] / 2;
    const int nTiles = (E + 31) / 32;

    const size_t hbElems = (size_t)nNodes * EMB;
    const size_t need    = hbElems * 2 + (16384 + 2048) * 2;

    if (ws_size >= need) {
        unsigned short* hb  = (unsigned short*)d_ws;
        unsigned short* tab = hb + hbElems;
        const int n8 = (int)(hbElems / 8);
        hipLaunchKernelGGL(conv_h_kernel, dim3((n8 + 255) / 256), dim3(256), 0, stream,
                           h, hb, n8);
        hipLaunchKernelGGL(pack_tabs, dim3(72), dim3(256), 0, stream, W1, W2, tab);
        hipLaunchKernelGGL(edge_mlp_r11, dim3(1024), dim3(256), 0, stream,
                           hb, tab, ei, b1, b2, out, E, nTiles);
    } else {
        hipLaunchKernelGGL(edge_mlp_naive, dim3((E + 255) / 256), dim3(256), 0, stream,
                           h, ei, W1, b1, W2, b2, out, E);
    }
}

// Round 12
// 83.796 us; speedup vs baseline: 1.1699x; 1.1699x over previous
//
#include <hip/hip_runtime.h>
#include <hip/hip_bf16.h>
#include <cstdint>

// EdgeMLP R12: int8 gather (1 line/endpoint instead of 2) + mfma_i32_16x16x64_i8
// (K=64 = one endpoint per MFMA). Per-16-node-group scales, held in LDS with
// sW pre-folded. Layer 2 = validated bf16 MFMA path. R9 depth-2 skeleton,
// no in-loop barriers, register ledger ~95.
// ws: [hq: nNodes*64 i8][scales: nG f32][sw f32][w1q: 16K i8][w2tab: 2048 bf16]

constexpr int EMB = 64;
constexpr int HID = 128;

typedef int   i32x4 __attribute__((ext_vector_type(4)));
typedef short s16x8 __attribute__((ext_vector_type(8)));
typedef float f32x4 __attribute__((ext_vector_type(4)));

__device__ __forceinline__ unsigned short f2bf(float x) {
    unsigned u = __float_as_uint(x);
    u = (u + 0x7fffu + ((u >> 16) & 1u)) >> 16;   // RNE
    return (unsigned short)u;
}

// ---- prep A: global max|W1| -> sw ----
__global__ void w1max_kernel(const float* __restrict__ W1, float* __restrict__ swp) {
    __shared__ float red[4];
    float m = 0.f;
    for (int i = threadIdx.x; i < 16384; i += 256) m = fmaxf(m, fabsf(W1[i]));
    #pragma unroll
    for (int off = 1; off < 64; off <<= 1) m = fmaxf(m, __shfl_xor(m, off, 64));
    if ((threadIdx.x & 63) == 0) red[threadIdx.x >> 6] = m;
    __syncthreads();
    if (threadIdx.x == 0)
        swp[0] = fmaxf(fmaxf(fmaxf(red[0], red[1]), fmaxf(red[2], red[3])) / 127.f, 1e-20f);
}

// ---- prep B: per-16-node-group scales ----
__global__ void node_scales(const float* __restrict__ h, float* __restrict__ sc,
                            int total) {
    __shared__ float red[4];
    const int g = blockIdx.x, t = threadIdx.x;
    const int base = g * 1024 + t * 4;
    float m = 0.f;
    if (base + 4 <= total) {
        float4 v = *reinterpret_cast<const float4*>(h + base);
        m = fmaxf(fmaxf(fabsf(v.x), fabsf(v.y)), fmaxf(fabsf(v.z), fabsf(v.w)));
    } else {
        for (int k = base; k < total; ++k) m = fmaxf(m, fabsf(h[k]));
    }
    #pragma unroll
    for (int off = 1; off < 64; off <<= 1) m = fmaxf(m, __shfl_xor(m, off, 64));
    if ((t & 63) == 0) red[t >> 6] = m;
    __syncthreads();
    if (t == 0)
        sc[g] = fmaxf(fmaxf(fmaxf(red[0], red[1]), fmaxf(red[2], red[3])) / 127.f, 1e-20f);
}

// ---- prep C: quantize h -> i8 (thread = 16 elems = 16 B) ----
__global__ void quant_h(const float* __restrict__ h, const float* __restrict__ sc,
                        char* __restrict__ hq, int nQuads) {
    const int i = blockIdx.x * blockDim.x + threadIdx.x;
    if (i >= nQuads) return;
    const float inv = 1.0f / sc[i >> 6];   // node = i>>2, group = node>>4
    const float* p = h + (size_t)i * 16;
    unsigned w[4];
    #pragma unroll
    for (int q = 0; q < 4; ++q) {
        float4 v = *reinterpret_cast<const float4*>(p + q * 4);
        int a = max(-127, min(127, __float2int_rn(v.x * inv)));
        int b = max(-127, min(127, __float2int_rn(v.y * inv)));
        int c = max(-127, min(127, __float2int_rn(v.z * inv)));
        int d = max(-127, min(127, __float2int_rn(v.w * inv)));
        w[q] = (a & 255) | ((b & 255) << 8) | ((c & 255) << 16) | ((unsigned)(d & 255) << 24);
    }
    *reinterpret_cast<uint4*>(hq + (size_t)i * 16) = make_uint4(w[0], w[1], w[2], w[3]);
}

// ---- prep D: W1 i8 fragments + W2 bf16 fragments ----
// w1q byte i = ((mt*2+half)*64+lane)*16 + j : q(W1[k][n]), k = half*64+(lane>>4)*16+j,
//                                             n = mt*16+(lane&15)
// w2tab (validated): q=(ks*64+lane)*8+j : tc=lane&15,bq=lane>>4; mt=ks*2+(j>>2),r=j&3;
//   val = (tc<2) ? bf16(W2[(mt*16+bq*4+r)*2+tc]) : 0
__global__ void pack_tabs_i8(const float* __restrict__ W1, const float* __restrict__ W2,
                             const float* __restrict__ swp,
                             char* __restrict__ w1q, unsigned short* __restrict__ w2t) {
    const int i = blockIdx.x * blockDim.x + threadIdx.x;
    if (i < 16384) {
        const int j = i & 15, lane = (i >> 4) & 63, half = (i >> 10) & 1, mt = i >> 11;
        const int k = half * 64 + (lane >> 4) * 16 + j;
        const int n = mt * 16 + (lane & 15);
        const float inv = 1.0f / swp[0];
        w1q[i] = (char)max(-127, min(127, __float2int_rn(W1[(size_t)k * HID + n] * inv)));
    } else if (i < 16384 + 2048) {
        const int q = i - 16384;
        const int j = q & 7, lane = (q >> 3) & 63, ks = q >> 9;
        const int tc = lane & 15, bq = lane >> 4;
        const int mt = ks * 2 + (j >> 2), r = j & 3;
        w2t[q] = (tc < 2) ? f2bf(W2[(mt * 16 + bq * 4 + r) * 2 + tc]) : (unsigned short)0;
    }
}

// ---- main ----
__global__ __launch_bounds__(256, 2)
void edge_mlp_i8(const char* __restrict__ hq,
                 const float* __restrict__ scg,
                 const float* __restrict__ swp,
                 const char* __restrict__ w1q,
                 const unsigned short* __restrict__ w2t,
                 const int* __restrict__ eidx,
                 const float* __restrict__ b1,
                 const float* __restrict__ b2,
                 float* __restrict__ out, int E, int nTiles, int nG)
{
    __shared__ uint4 w1s[1024];   // 16 KB i8 W1 fragments
    __shared__ float sS[6272];    // 25.1 KB group scales (pre-folded with sw)
    __shared__ float b1s[128];
    {
        const uint4* src = reinterpret_cast<const uint4*>(w1q);
        #pragma unroll
        for (int r = 0; r < 4; ++r)
            w1s[r * 256 + threadIdx.x] = src[r * 256 + threadIdx.x];
        const float swv = swp[0];
        for (int i = threadIdx.x; i < nG; i += 256) sS[i] = scg[i] * swv;
        if (threadIdx.x < 128) b1s[threadIdx.x] = b1[threadIdx.x];
    }
    __syncthreads();

    const int t = threadIdx.x, wid = t >> 6, lane = t & 63;
    const int tc = lane & 15, bq = lane >> 4;
    const i32x4* wq = reinterpret_cast<const i32x4*>(w1s) + lane;  // + (mt*2+half)*64
    const float* b1v = b1s + bq * 4;                               // + mt*16

    // W2 fragments persistent in registers (validated path)
    s16x8 w2f[4];
    #pragma unroll
    for (int ks = 0; ks < 4; ++ks)
        w2f[ks] = *reinterpret_cast<const s16x8*>(w2t + (ks * 64 + lane) * 8);

    const float a20 = (bq == 0) ? b2[0] : 0.f;
    const float a21 = (bq == 0) ? b2[1] : 0.f;

    const int stride = gridDim.x * 4;
    int tile = blockIdx.x * 4 + wid;
    if (tile >= nTiles) return;

    auto LOADIDX = [&](int tl, int& s, int& d) {
        if (tl < nTiles) {
            const int e = min(tl * 16 + tc, E - 1);
            s = eidx[e]; d = eidx[E + e];
        } else { s = 0; d = 0; }
    };
    auto GATHER = [&](int s, int d, i32x4& xS, i32x4& xD, float& ssw, float& sdw) {
        xS = *reinterpret_cast<const i32x4*>(hq + (size_t)s * EMB + bq * 16);
        xD = *reinterpret_cast<const i32x4*>(hq + (size_t)d * EMB + bq * 16);
        ssw = sS[s >> 4];
        sdw = sS[d >> 4];
    };
    auto COMPUTE = [&](int tl, i32x4 xS, i32x4 xD, float ssw, float sdw) {
        const i32x4 z = {0, 0, 0, 0};
        f32x4 o = {a20, a21, 0.f, 0.f};
        #pragma unroll
        for (int ks2 = 0; ks2 < 4; ++ks2) {
            const int mt0 = ks2 * 2, mt1 = mt0 + 1;
            i32x4 aS0 = __builtin_amdgcn_mfma_i32_16x16x64_i8(wq[(mt0 * 2 + 0) * 64], xS, z, 0, 0, 0);
            i32x4 aD0 = __builtin_amdgcn_mfma_i32_16x16x64_i8(wq[(mt0 * 2 + 1) * 64], xD, z, 0, 0, 0);
            i32x4 aS1 = __builtin_amdgcn_mfma_i32_16x16x64_i8(wq[(mt1 * 2 + 0) * 64], xS, z, 0, 0, 0);
            i32x4 aD1 = __builtin_amdgcn_mfma_i32_16x16x64_i8(wq[(mt1 * 2 + 1) * 64], xD, z, 0, 0, 0);
            const f32x4 bb0 = *reinterpret_cast<const f32x4*>(b1v + mt0 * 16);
            const f32x4 bb1 = *reinterpret_cast<const f32x4*>(b1v + mt1 * 16);
            s16x8 p;
            #pragma unroll
            for (int jj = 0; jj < 4; ++jj) {
                const int r = (jj & 1) * 2;
                float h0, h1;
                if (jj < 2) {
                    h0 = fmaxf(fmaf((float)aS0[r],     ssw, fmaf((float)aD0[r],     sdw, bb0[r]    )), 0.f);
                    h1 = fmaxf(fmaf((float)aS0[r + 1], ssw, fmaf((float)aD0[r + 1], sdw, bb0[r + 1])), 0.f);
                } else {
                    h0 = fmaxf(fmaf((float)aS1[r],     ssw, fmaf((float)aD1[r],     sdw, bb1[r]    )), 0.f);
                    h1 = fmaxf(fmaf((float)aS1[r + 1], ssw, fmaf((float)aD1[r + 1], sdw, bb1[r + 1])), 0.f);
                }
                __hip_bfloat162 bb = __float22bfloat162_rn(make_float2(h0, h1));
                reinterpret_cast<unsigned*>(&p)[jj] = *reinterpret_cast<unsigned*>(&bb);
            }
            o = __builtin_amdgcn_mfma_f32_16x16x32_bf16(w2f[ks2], p, o, 0, 0, 0);
        }
        if (lane < 16) {
            const int eo = tl * 16 + lane;
            if (eo < E)
                *reinterpret_cast<float2*>(out + (size_t)eo * 2) = make_float2(o[0], o[1]);
        }
    };

    // ---- depth-2 pipeline, statically-named sets, no in-loop barrier ----
    int s0, d0, s1, d1;
    i32x4 xS0, xD0, xS1, xD1;
    float ssw0, sdw0, ssw1, sdw1;

    LOADIDX(tile, s0, d0);
    GATHER(s0, d0, xS0, xD0, ssw0, sdw0);
    LOADIDX(tile + stride, s1, d1);

    while (true) {
        GATHER(s1, d1, xS1, xD1, ssw1, sdw1);
        LOADIDX(tile + 2 * stride, s0, d0);
        COMPUTE(tile, xS0, xD0, ssw0, sdw0);
        tile += stride;
        if (tile >= nTiles) break;

        GATHER(s0, d0, xS0, xD0, ssw0, sdw0);
        LOADIDX(tile + 2 * stride, s1, d1);
        COMPUTE(tile, xS1, xD1, ssw1, sdw1);
        tile += stride;
        if (tile >= nTiles) break;
    }
}

// ---- fallback (ws too small; correct but slow) ----
__global__ void edge_mlp_naive(const float* __restrict__ h, const int* __restrict__ eidx,
                               const float* __restrict__ W1, const float* __restrict__ b1,
                               const float* __restrict__ W2, const float* __restrict__ b2,
                               float* __restrict__ out, int E) {
    const int e = blockIdx.x * 256 + threadIdx.x;
    if (e >= E) return;
    const float* hs = h + (size_t)eidx[e] * EMB;
    const float* hd = h + (size_t)eidx[E + e] * EMB;
    float o0 = b2[0], o1 = b2[1];
    for (int j = 0; j < HID; ++j) {
        float a = b1[j];
        for (int k = 0; k < EMB; ++k)
            a += hs[k] * W1[(size_t)k * HID + j] + hd[k] * W1[(size_t)(k + EMB) * HID + j];
        a = fmaxf(a, 0.f);
        o0 = fmaf(a, W2[j * 2 + 0], o0);
        o1 = fmaf(a, W2[j * 2 + 1], o1);
    }
    out[(size_t)e * 2 + 0] = o0;
    out[(size_t)e * 2 + 1] = o1;
}

extern "C" void kernel_launch(void* const* d_in, const int* in_sizes, int n_in,
                              void* d_out, int out_size, void* d_ws, size_t ws_size,
                              hipStream_t stream)
{
    const float* h  = (const float*)d_in[0];
    const int*   ei = (const int*)d_in[1];
    const float* W1 = (const float*)d_in[2];
    const float* b1 = (const float*)d_in[3];
    const float* W2 = (const float*)d_in[4];
    const float* b2 = (const float*)d_in[5];
    float* out = (float*)d_out;

    const int nNodes = in_sizes[0] / EMB;
    const int E      = in_sizes[1] / 2;
    const int nTiles = (E + 15) / 16;
    const int nG     = (nNodes + 15) >> 4;
    const int total  = nNodes * EMB;

    // ws layout
    const size_t hq_off = 0;
    const size_t sc_off = (size_t)nNodes * EMB;            // 64B-aligned
    const size_t sw_off = sc_off + (size_t)nG * 4;
    const size_t w1_off = (sw_off + 4 + 15) & ~(size_t)15;
    const size_t w2_off = w1_off + 16384;
    const size_t need   = w2_off + 2048 * 2;

    if (ws_size >= need && nG <= 6272) {
        char*  ws  = (char*)d_ws;
        char*  hq  = ws + hq_off;
        float* scg = (float*)(ws + sc_off);
        float* swp = (float*)(ws + sw_off);
        char*  w1q = ws + w1_off;
        unsigned short* w2t = (unsigned short*)(ws + w2_off);

        hipLaunchKernelGGL(w1max_kernel, dim3(1), dim3(256), 0, stream, W1, swp);
        hipLaunchKernelGGL(node_scales, dim3(nG), dim3(256), 0, stream, h, scg, total);
        hipLaunchKernelGGL(quant_h, dim3((nNodes * 4 + 255) / 256), dim3(256), 0, stream,
                           h, scg, hq, nNodes * 4);
        hipLaunchKernelGGL(pack_tabs_i8, dim3(72), dim3(256), 0, stream,
                           W1, W2, swp, w1q, w2t);
        hipLaunchKernelGGL(edge_mlp_i8, dim3(768), dim3(256), 0, stream,
                           hq, scg, swp, w1q, w2t, ei, b1, b2, out, E, nTiles, nG);
    } else {
        hipLaunchKernelGGL(edge_mlp_naive, dim3((E + 255) / 256), dim3(256), 0, stream,
                           h, ei, W1, b1, W2, b2, out, E);
    }
}

// Round 14
// 75.340 us; speedup vs baseline: 1.3012x; 1.1122x over previous
//
#include <hip/hip_runtime.h>
#include <hip/hip_bf16.h>
#include <cstdint>

// EdgeMLP R14 = R13 with the W1-quant scale bug fixed (inv = 127/max, was 1/max).
//   i8 gather (1 line/endpoint) + mfma_i32_16x16x64_i8, per-64-node scales,
//   depth-3 gather pipeline, fused single-pass h max+quant prep.
// ws: [hq: nNodes*64 i8][sc: nG64 f32][swbits u32][w1q 16K i8][w2tab 2048 bf16]

constexpr int EMB = 64;
constexpr int HID = 128;

typedef int   i32x4 __attribute__((ext_vector_type(4)));
typedef short s16x8 __attribute__((ext_vector_type(8)));
typedef float f32x4 __attribute__((ext_vector_type(4)));

__device__ __forceinline__ unsigned short f2bf(float x) {
    unsigned u = __float_as_uint(x);
    u = (u + 0x7fffu + ((u >> 16) & 1u)) >> 16;   // RNE
    return (unsigned short)u;
}

// ---- prep A: global max|W1| via per-wave atomicMax on float bits ----
__global__ void w1max_kernel(const float* __restrict__ W1, unsigned* __restrict__ swbits) {
    const int i = blockIdx.x * 256 + threadIdx.x;   // grid 16 -> 4096 thr x 4 elems
    float4 v = *reinterpret_cast<const float4*>(W1 + (size_t)i * 4);
    float m = fmaxf(fmaxf(fabsf(v.x), fabsf(v.y)), fmaxf(fabsf(v.z), fabsf(v.w)));
    #pragma unroll
    for (int off = 1; off < 64; off <<= 1) m = fmaxf(m, __shfl_xor(m, off, 64));
    if ((threadIdx.x & 63) == 0) atomicMax(swbits, __float_as_uint(m));
}

// ---- prep B: fused per-64-node-group max + quantize (single pass over h) ----
__global__ void quant_h_fused(const float* __restrict__ h, float* __restrict__ sc,
                              char* __restrict__ hq, int total) {
    __shared__ float red[4];
    const int g = blockIdx.x, t = threadIdx.x;
    const size_t base = (size_t)g * 4096 + (size_t)t * 16;   // 16 f32 per thread
    const bool full = (base < (size_t)total);                // total % 16 == 0
    float4 v[4];
    float m = 0.f;
    if (full) {
        #pragma unroll
        for (int q = 0; q < 4; ++q) {
            v[q] = *reinterpret_cast<const float4*>(h + base + q * 4);
            m = fmaxf(m, fmaxf(fmaxf(fabsf(v[q].x), fabsf(v[q].y)),
                               fmaxf(fabsf(v[q].z), fabsf(v[q].w))));
        }
    }
    #pragma unroll
    for (int off = 1; off < 64; off <<= 1) m = fmaxf(m, __shfl_xor(m, off, 64));
    if ((t & 63) == 0) red[t >> 6] = m;
    __syncthreads();
    const float gmax = fmaxf(fmaxf(red[0], red[1]), fmaxf(red[2], red[3]));
    const float scale = fmaxf(gmax / 127.f, 1e-20f);
    if (t == 0) sc[g] = scale;
    if (!full) return;
    const float inv = 1.0f / scale;
    unsigned w[4];
    #pragma unroll
    for (int q = 0; q < 4; ++q) {
        int a = max(-127, min(127, __float2int_rn(v[q].x * inv)));
        int b = max(-127, min(127, __float2int_rn(v[q].y * inv)));
        int c = max(-127, min(127, __float2int_rn(v[q].z * inv)));
        int d = max(-127, min(127, __float2int_rn(v[q].w * inv)));
        w[q] = (a & 255) | ((b & 255) << 8) | ((c & 255) << 16) | ((unsigned)(d & 255) << 24);
    }
    *reinterpret_cast<uint4*>(hq + base) = make_uint4(w[0], w[1], w[2], w[3]);
}

// ---- prep C: W1 i8 fragments + W2 bf16 fragments (R12-validated layouts) ----
__global__ void pack_tabs_i8(const float* __restrict__ W1, const float* __restrict__ W2,
                             const float* __restrict__ swp,
                             char* __restrict__ w1q, unsigned short* __restrict__ w2t) {
    const int i = blockIdx.x * blockDim.x + threadIdx.x;
    if (i < 16384) {
        const int j = i & 15, lane = (i >> 4) & 63, half = (i >> 10) & 1, mt = i >> 11;
        const int k = half * 64 + (lane >> 4) * 16 + j;
        const int n = mt * 16 + (lane & 15);
        const float inv = 127.f / fmaxf(swp[0], 1e-18f);   // FIX: 1/sw = 127/max
        w1q[i] = (char)max(-127, min(127, __float2int_rn(W1[(size_t)k * HID + n] * inv)));
    } else if (i < 16384 + 2048) {
        const int q = i - 16384;
        const int j = q & 7, lane = (q >> 3) & 63, ks = q >> 9;
        const int tc = lane & 15, bq = lane >> 4;
        const int mt = ks * 2 + (j >> 2), r = j & 3;
        w2t[q] = (tc < 2) ? f2bf(W2[(mt * 16 + bq * 4 + r) * 2 + tc]) : (unsigned short)0;
    }
}

// ---- main ----
__global__ __launch_bounds__(256, 2)
void edge_mlp_i8v2(const char* __restrict__ hq,
                   const float* __restrict__ scg,
                   const float* __restrict__ swp,
                   const char* __restrict__ w1q,
                   const unsigned short* __restrict__ w2t,
                   const int* __restrict__ eidx,
                   const float* __restrict__ b1,
                   const float* __restrict__ b2,
                   float* __restrict__ out, int E, int nTiles, int nG64)
{
    __shared__ uint4 w1s[1024];   // 16 KB i8 W1 fragments
    __shared__ float sS[1600];    // 6.4 KB per-64-node scales (sw pre-folded)
    __shared__ float b1s[128];
    {
        const uint4* src = reinterpret_cast<const uint4*>(w1q);
        #pragma unroll
        for (int r = 0; r < 4; ++r)
            w1s[r * 256 + threadIdx.x] = src[r * 256 + threadIdx.x];
        const float swv = swp[0] / 127.f;   // swbits holds max|W1|; sw = max/127
        for (int i = threadIdx.x; i < nG64; i += 256) sS[i] = scg[i] * swv;
        if (threadIdx.x < 128) b1s[threadIdx.x] = b1[threadIdx.x];
    }
    __syncthreads();

    const int t = threadIdx.x, wid = t >> 6, lane = t & 63;
    const int tc = lane & 15, bq = lane >> 4;
    const i32x4* wq = reinterpret_cast<const i32x4*>(w1s) + lane;  // + (mt*2+half)*64
    const float* b1v = b1s + bq * 4;                               // + mt*16

    s16x8 w2f[4];
    #pragma unroll
    for (int ks = 0; ks < 4; ++ks)
        w2f[ks] = *reinterpret_cast<const s16x8*>(w2t + (ks * 64 + lane) * 8);

    const float a20 = (bq == 0) ? b2[0] : 0.f;
    const float a21 = (bq == 0) ? b2[1] : 0.f;

    const int stride = gridDim.x * 4;
    int tile = blockIdx.x * 4 + wid;
    if (tile >= nTiles) return;

    auto LOADIDX = [&](int tl, int& s, int& d) {
        if (tl < nTiles) {
            const int e = min(tl * 16 + tc, E - 1);
            s = eidx[e]; d = eidx[E + e];
        } else { s = 0; d = 0; }
    };
    auto GATHER = [&](int s, int d, i32x4& xS, i32x4& xD, float& ssw, float& sdw) {
        xS = *reinterpret_cast<const i32x4*>(hq + (size_t)s * EMB + bq * 16);
        xD = *reinterpret_cast<const i32x4*>(hq + (size_t)d * EMB + bq * 16);
        ssw = sS[s >> 6];
        sdw = sS[d >> 6];
    };
    auto COMPUTE = [&](int tl, i32x4 xS, i32x4 xD, float ssw, float sdw) {
        const i32x4 z = {0, 0, 0, 0};
        f32x4 o = {a20, a21, 0.f, 0.f};
        #pragma unroll
        for (int ks2 = 0; ks2 < 4; ++ks2) {
            const int mt0 = ks2 * 2, mt1 = mt0 + 1;
            i32x4 aS0 = __builtin_amdgcn_mfma_i32_16x16x64_i8(wq[(mt0 * 2 + 0) * 64], xS, z, 0, 0, 0);
            i32x4 aD0 = __builtin_amdgcn_mfma_i32_16x16x64_i8(wq[(mt0 * 2 + 1) * 64], xD, z, 0, 0, 0);
            i32x4 aS1 = __builtin_amdgcn_mfma_i32_16x16x64_i8(wq[(mt1 * 2 + 0) * 64], xS, z, 0, 0, 0);
            i32x4 aD1 = __builtin_amdgcn_mfma_i32_16x16x64_i8(wq[(mt1 * 2 + 1) * 64], xD, z, 0, 0, 0);
            const f32x4 bb0 = *reinterpret_cast<const f32x4*>(b1v + mt0 * 16);
            const f32x4 bb1 = *reinterpret_cast<const f32x4*>(b1v + mt1 * 16);
            s16x8 p;
            #pragma unroll
            for (int jj = 0; jj < 4; ++jj) {
                const int r = (jj & 1) * 2;
                float h0, h1;
                if (jj < 2) {
                    h0 = fmaxf(fmaf((float)aS0[r],     ssw, fmaf((float)aD0[r],     sdw, bb0[r]    )), 0.f);
                    h1 = fmaxf(fmaf((float)aS0[r + 1], ssw, fmaf((float)aD0[r + 1], sdw, bb0[r + 1])), 0.f);
                } else {
                    h0 = fmaxf(fmaf((float)aS1[r],     ssw, fmaf((float)aD1[r],     sdw, bb1[r]    )), 0.f);
                    h1 = fmaxf(fmaf((float)aS1[r + 1], ssw, fmaf((float)aD1[r + 1], sdw, bb1[r + 1])), 0.f);
                }
                __hip_bfloat162 bb = __float22bfloat162_rn(make_float2(h0, h1));
                reinterpret_cast<unsigned*>(&p)[jj] = *reinterpret_cast<unsigned*>(&bb);
            }
            o = __builtin_amdgcn_mfma_f32_16x16x32_bf16(w2f[ks2], p, o, 0, 0, 0);
        }
        if (lane < 16) {
            const int eo = tl * 16 + lane;
            if (eo < E)
                *reinterpret_cast<float2*>(out + (size_t)eo * 2) = make_float2(o[0], o[1]);
        }
    };

    // ---- depth-3 pipeline: gather-to-consume distance = 2 phases ----
    int s0, d0, s1, d1, s2, d2;
    i32x4 xS0, xD0, xS1, xD1, xS2, xD2;
    float w0s, w0d, w1sc, w1d, w2sc, w2d;

    LOADIDX(tile, s0, d0);
    GATHER(s0, d0, xS0, xD0, w0s, w0d);
    LOADIDX(tile + stride, s1, d1);
    GATHER(s1, d1, xS1, xD1, w1sc, w1d);
    LOADIDX(tile + 2 * stride, s2, d2);

    while (true) {
        GATHER(s2, d2, xS2, xD2, w2sc, w2d);
        LOADIDX(tile + 3 * stride, s0, d0);
        COMPUTE(tile, xS0, xD0, w0s, w0d);
        tile += stride;
        if (tile >= nTiles) break;

        GATHER(s0, d0, xS0, xD0, w0s, w0d);
        LOADIDX(tile + 3 * stride, s1, d1);
        COMPUTE(tile, xS1, xD1, w1sc, w1d);
        tile += stride;
        if (tile >= nTiles) break;

        GATHER(s1, d1, xS1, xD1, w1sc, w1d);
        LOADIDX(tile + 3 * stride, s2, d2);
        COMPUTE(tile, xS2, xD2, w2sc, w2d);
        tile += stride;
        if (tile >= nTiles) break;
    }
}

// ---- fallback (ws too small; correct but slow) ----
__global__ void edge_mlp_naive(const float* __restrict__ h, const int* __restrict__ eidx,
                               const float* __restrict__ W1, const float* __restrict__ b1,
                               const float* __restrict__ W2, const float* __restrict__ b2,
                               float* __restrict__ out, int E) {
    const int e = blockIdx.x * 256 + threadIdx.x;
    if (e >= E) return;
    const float* hs = h + (size_t)eidx[e] * EMB;
    const float* hd = h + (size_t)eidx[E + e] * EMB;
    float o0 = b2[0], o1 = b2[1];
    for (int j = 0; j < HID; ++j) {
        float a = b1[j];
        for (int k = 0; k < EMB; ++k)
            a += hs[k] * W1[(size_t)k * HID + j] + hd[k] * W1[(size_t)(k + EMB) * HID + j];
        a = fmaxf(a, 0.f);
        o0 = fmaf(a, W2[j * 2 + 0], o0);
        o1 = fmaf(a, W2[j * 2 + 1], o1);
    }
    out[(size_t)e * 2 + 0] = o0;
    out[(size_t)e * 2 + 1] = o1;
}

extern "C" void kernel_launch(void* const* d_in, const int* in_sizes, int n_in,
                              void* d_out, int out_size, void* d_ws, size_t ws_size,
                              hipStream_t stream)
{
    const float* h  = (const float*)d_in[0];
    const int*   ei = (const int*)d_in[1];
    const float* W1 = (const float*)d_in[2];
    const float* b1 = (const float*)d_in[3];
    const float* W2 = (const float*)d_in[4];
    const float* b2 = (const float*)d_in[5];
    float* out = (float*)d_out;

    const int nNodes = in_sizes[0] / EMB;
    const int E      = in_sizes[1] / 2;
    const int nTiles = (E + 15) / 16;
    const int nG64   = (nNodes + 63) >> 6;
    const int total  = nNodes * EMB;

    const size_t hq_off = 0;
    const size_t sc_off = (size_t)nNodes * EMB;
    const size_t sw_off = sc_off + (size_t)nG64 * 4;
    const size_t w1_off = (sw_off + 4 + 15) & ~(size_t)15;
    const size_t w2_off = w1_off + 16384;
    const size_t need   = w2_off + 2048 * 2;

    if (ws_size >= need && nG64 <= 1600) {
        char*  ws  = (char*)d_ws;
        char*  hq  = ws + hq_off;
        float* scg = (float*)(ws + sc_off);
        unsigned* swb = (unsigned*)(ws + sw_off);
        char*  w1q = ws + w1_off;
        unsigned short* w2t = (unsigned short*)(ws + w2_off);

        hipMemsetAsync(swb, 0, 4, stream);
        hipLaunchKernelGGL(w1max_kernel, dim3(16), dim3(256), 0, stream, W1, swb);
        hipLaunchKernelGGL(quant_h_fused, dim3(nG64), dim3(256), 0, stream,
                           h, scg, hq, total);
        hipLaunchKernelGGL(pack_tabs_i8, dim3(72), dim3(256), 0, stream,
                           W1, W2, (const float*)swb, w1q, w2t);
        hipLaunchKernelGGL(edge_mlp_i8v2, dim3(1024), dim3(256), 0, stream,
                           hq, scg, (const float*)swb, w1q, w2t, ei, b1, b2,
                           out, E, nTiles, nG64);
    } else {
        hipLaunchKernelGGL(edge_mlp_naive, dim3((E + 255) / 256), dim3(256), 0, stream,
                           h, ei, W1, b1, W2, b2, out, E);
    }
}